// Round 2
// baseline (132.321 us; speedup 1.0000x reference)
//
#include <hip/hip_runtime.h>

// SSIM loss: predict/gt (32,1,512,512) f32, 11-tap separable gaussian (sigma=1.5),
// VALID padding -> 502x502 per image, loss = 1 - mean(ssim_map).
//
// Round 2 structure: LDS-pipe-bound fix. Transposed input staging so the
// vertical pass reads taps as contiguous b128; register-blocked (4 outputs /
// thread) in both passes; all LDS reads are ds_read_b128.

constexpr int WIN = 11;
constexpr int TILE = 32;
constexpr int INT_ = TILE + WIN - 1;      // 42 input tile
constexpr int PAD = 44;                   // padded to multiple of 4 (16B rows)
constexpr int H = 512, W = 512, NIMG = 32;
constexpr int OH = H - WIN + 1, OW = W - WIN + 1;  // 502
constexpr float C1 = 0.009801f;   // (0.01*9.9)^2
constexpr float C2 = 0.088209f;   // (0.03*9.9)^2
constexpr double TOTAL = (double)NIMG * (double)OH * (double)OW;

__global__ void zero_acc_kernel(float* acc) {
    if (threadIdx.x == 0) acc[0] = 0.f;
}

__global__ void finalize_kernel(const float* __restrict__ acc, float* __restrict__ out) {
    if (threadIdx.x == 0) out[0] = 1.f - acc[0];
}

__global__ __launch_bounds__(256) void ssim_main_kernel(const float* __restrict__ P,
                                                        const float* __restrict__ G,
                                                        float* __restrict__ acc) {
    // transposed input tiles: [col][row] so vertical taps are contiguous
    __shared__ float spT[PAD][PAD];
    __shared__ float sgT[PAD][PAD];
    // vertically blurred channels, row-major: [q][row][col]
    __shared__ float sv[5][TILE][PAD];

    const int tid = threadIdx.x;
    const int bid = blockIdx.x;
    const int img = bid >> 8;            // 256 tiles per image (16x16)
    const int t = bid & 255;
    const int oy0 = (t >> 4) * TILE;
    const int ox0 = (t & 15) * TILE;

    const float* p = P + (size_t)img * H * W;
    const float* g = G + (size_t)img * H * W;

    // gaussian weights
    float wgt[WIN];
    {
        float s = 0.f;
#pragma unroll
        for (int i = 0; i < WIN; ++i) {
            float c = (float)(i - WIN / 2);
            wgt[i] = __expf(-(c * c) / 4.5f);   // 2*sigma^2 = 4.5
            s += wgt[i];
        }
        float inv = 1.f / s;
#pragma unroll
        for (int i = 0; i < WIN; ++i) wgt[i] *= inv;
    }

    // ---- stage (transposed): 42 rows x 11 float4 col-groups per channel
    for (int idx = tid; idx < INT_ * 11; idx += 256) {
        const int r = idx / 11, f4 = idx % 11;
        const int gr = min(oy0 + r, H - 1);
        const int gc = ox0 + f4 * 4;
        float4 vp, vg;
        if (gc + 3 < W) {
            vp = *(const float4*)(p + gr * W + gc);
            vg = *(const float4*)(g + gr * W + gc);
        } else {
            const int c0 = min(gc, W - 1), c1 = min(gc + 1, W - 1);
            const int c2 = min(gc + 2, W - 1), c3 = min(gc + 3, W - 1);
            vp = make_float4(p[gr * W + c0], p[gr * W + c1], p[gr * W + c2], p[gr * W + c3]);
            vg = make_float4(g[gr * W + c0], g[gr * W + c1], g[gr * W + c2], g[gr * W + c3]);
        }
        const int c = f4 * 4;
        spT[c + 0][r] = vp.x; spT[c + 1][r] = vp.y; spT[c + 2][r] = vp.z; spT[c + 3][r] = vp.w;
        sgT[c + 0][r] = vg.x; sgT[c + 1][r] = vg.y; sgT[c + 2][r] = vg.z; sgT[c + 3][r] = vg.w;
    }
    __syncthreads();

    // ---- vertical pass: thread = (col, row-group of 4); 44 cols x 8 groups = 352 tasks
    for (int t2 = tid; t2 < PAD * 8; t2 += 256) {
        const int c = t2 % PAD, rg = t2 / PAD;
        const float* pc = &spT[c][0];
        const float* gc = &sgT[c][0];
        float pv[16], gv[16];
#pragma unroll
        for (int i = 0; i < 4; ++i) {
            const float4 a = *(const float4*)(pc + 4 * rg + 4 * i);
            const float4 b = *(const float4*)(gc + 4 * rg + 4 * i);
            pv[4 * i + 0] = a.x; pv[4 * i + 1] = a.y; pv[4 * i + 2] = a.z; pv[4 * i + 3] = a.w;
            gv[4 * i + 0] = b.x; gv[4 * i + 1] = b.y; gv[4 * i + 2] = b.z; gv[4 * i + 3] = b.w;
        }
        // unique products for taps (rows rg*4 .. rg*4+13 -> elements 0..13)
        float pp[14], gg[14], pg[14];
#pragma unroll
        for (int e = 0; e < 14; ++e) {
            pp[e] = pv[e] * pv[e];
            gg[e] = gv[e] * gv[e];
            pg[e] = pv[e] * gv[e];
        }
#pragma unroll
        for (int j = 0; j < 4; ++j) {
            float a0 = 0.f, a1 = 0.f, a2 = 0.f, a3 = 0.f, a4 = 0.f;
#pragma unroll
            for (int k = 0; k < WIN; ++k) {
                const float w = wgt[k];
                a0 += w * pv[j + k];
                a1 += w * gv[j + k];
                a2 += w * pp[j + k];
                a3 += w * gg[j + k];
                a4 += w * pg[j + k];
            }
            const int r = rg * 4 + j;
            sv[0][r][c] = a0; sv[1][r][c] = a1; sv[2][r][c] = a2;
            sv[3][r][c] = a3; sv[4][r][c] = a4;
        }
    }
    __syncthreads();

    // ---- horizontal pass + SSIM: thread = (row, col-group of 4); 32 x 8 = 256 tasks
    float lsum = 0.f;
    {
        const int r = tid >> 3;
        const int c0 = (tid & 7) * 4;
        float q[5][16];
#pragma unroll
        for (int qq = 0; qq < 5; ++qq) {
#pragma unroll
            for (int i = 0; i < 4; ++i) {
                const float4 a = *(const float4*)(&sv[qq][r][c0 + 4 * i]);
                q[qq][4 * i + 0] = a.x; q[qq][4 * i + 1] = a.y;
                q[qq][4 * i + 2] = a.z; q[qq][4 * i + 3] = a.w;
            }
        }
        const bool rowok = (oy0 + r) < OH;
#pragma unroll
        for (int cc = 0; cc < 4; ++cc) {
            float m1 = 0.f, m2 = 0.f, e11 = 0.f, e22 = 0.f, e12 = 0.f;
#pragma unroll
            for (int k = 0; k < WIN; ++k) {
                const float w = wgt[k];
                m1  += w * q[0][cc + k];
                m2  += w * q[1][cc + k];
                e11 += w * q[2][cc + k];
                e22 += w * q[3][cc + k];
                e12 += w * q[4][cc + k];
            }
            const float mu11 = m1 * m1, mu22 = m2 * m2, mu12 = m1 * m2;
            const float s11 = e11 - mu11, s22 = e22 - mu22, s12 = e12 - mu12;
            const float cs = (2.f * s12 + C2) / (s11 + s22 + C2);
            const float ssim = ((2.f * mu12 + C1) / (mu11 + mu22 + C1)) * cs;
            const bool ok = rowok && ((ox0 + c0 + cc) < OW);
            lsum += ok ? ssim : 0.f;
        }
    }

    // ---- block reduction: wave64 shuffle, then cross-wave via LDS
#pragma unroll
    for (int off = 32; off > 0; off >>= 1)
        lsum += __shfl_down(lsum, off, 64);

    __shared__ float wsum[4];
    const int wid = tid >> 6, lane = tid & 63;
    if (lane == 0) wsum[wid] = lsum;
    __syncthreads();
    if (tid == 0) {
        const float bs = wsum[0] + wsum[1] + wsum[2] + wsum[3];
        atomicAdd(acc, bs * (float)(1.0 / TOTAL));
    }
}

extern "C" void kernel_launch(void* const* d_in, const int* in_sizes, int n_in,
                              void* d_out, int out_size, void* d_ws, size_t ws_size,
                              hipStream_t stream) {
    const float* P = (const float*)d_in[0];   // predict
    const float* G = (const float*)d_in[1];   // gt
    float* out = (float*)d_out;
    float* acc = (float*)d_ws;

    zero_acc_kernel<<<1, 64, 0, stream>>>(acc);
    ssim_main_kernel<<<NIMG * 16 * 16, 256, 0, stream>>>(P, G, acc);
    finalize_kernel<<<1, 64, 0, stream>>>(acc, out);
}

// Round 3
// 130.017 us; speedup vs baseline: 1.0177x; 1.0177x over previous
//
#include <hip/hip_runtime.h>

// SSIM loss: predict/gt (32,1,512,512) f32, 11-tap separable gaussian (sigma=1.5),
// VALID padding -> 502x502 per image, loss = 1 - mean(ssim_map).
//
// Round 3: remove staging bank conflicts. Stage via register 4x4 transpose ->
// b128 column writes, row-quad-major task order (conflict-free in aligned
// 8-lane windows). Vertical/horizontal passes unchanged (b128, clean).

constexpr int WIN = 11;
constexpr int TILE = 32;
constexpr int PAD = 44;                   // 42 used, padded to multiple of 4
constexpr int H = 512, W = 512, NIMG = 32;
constexpr int OH = H - WIN + 1, OW = W - WIN + 1;  // 502
constexpr float C1 = 0.009801f;   // (0.01*9.9)^2
constexpr float C2 = 0.088209f;   // (0.03*9.9)^2
constexpr double TOTAL = (double)NIMG * (double)OH * (double)OW;

__global__ void zero_acc_kernel(float* acc) {
    if (threadIdx.x == 0) acc[0] = 0.f;
}

__global__ void finalize_kernel(const float* __restrict__ acc, float* __restrict__ out) {
    if (threadIdx.x == 0) out[0] = 1.f - acc[0];
}

__global__ __launch_bounds__(256) void ssim_main_kernel(const float* __restrict__ P,
                                                        const float* __restrict__ G,
                                                        float* __restrict__ acc) {
    // transposed input tiles: [col][row], column segments written as b128
    __shared__ float spT[PAD][PAD];
    __shared__ float sgT[PAD][PAD];
    // vertically blurred channels, row-major: [q][row][col]
    __shared__ float sv[5][TILE][PAD];

    const int tid = threadIdx.x;
    const int bid = blockIdx.x;
    const int img = bid >> 8;            // 256 tiles per image (16x16)
    const int t = bid & 255;
    const int oy0 = (t >> 4) * TILE;
    const int ox0 = (t & 15) * TILE;

    const float* p = P + (size_t)img * H * W;
    const float* g = G + (size_t)img * H * W;

    // gaussian weights
    float wgt[WIN];
    {
        float s = 0.f;
#pragma unroll
        for (int i = 0; i < WIN; ++i) {
            float c = (float)(i - WIN / 2);
            wgt[i] = __expf(-(c * c) / 4.5f);   // 2*sigma^2 = 4.5
            s += wgt[i];
        }
        float inv = 1.f / s;
#pragma unroll
        for (int i = 0; i < WIN; ++i) wgt[i] *= inv;
    }

    // ---- stage (register 4x4 transpose): 11 col-groups x 11 row-quads = 121 tasks
    // task order rq-major: bank-group = (4*f4 + 3*j + rq) mod 8 -> conflict-free
    for (int t2 = tid; t2 < 121; t2 += 256) {
        const int rq = t2 % 11, f4 = t2 / 11;
        const int gcol = ox0 + f4 * 4;
        float4 vp[4], vg[4];
#pragma unroll
        for (int i = 0; i < 4; ++i) {
            const int gr = min(oy0 + 4 * rq + i, H - 1);
            if (gcol + 3 < W) {
                vp[i] = *(const float4*)(p + gr * W + gcol);
                vg[i] = *(const float4*)(g + gr * W + gcol);
            } else {
                const int c0 = min(gcol, W - 1), c1 = min(gcol + 1, W - 1);
                const int c2 = min(gcol + 2, W - 1), c3 = min(gcol + 3, W - 1);
                vp[i] = make_float4(p[gr * W + c0], p[gr * W + c1], p[gr * W + c2], p[gr * W + c3]);
                vg[i] = make_float4(g[gr * W + c0], g[gr * W + c1], g[gr * W + c2], g[gr * W + c3]);
            }
        }
        const int r0 = 4 * rq;
#pragma unroll
        for (int j = 0; j < 4; ++j) {
            const float4 cp = make_float4(((const float*)&vp[0])[j], ((const float*)&vp[1])[j],
                                          ((const float*)&vp[2])[j], ((const float*)&vp[3])[j]);
            const float4 cg = make_float4(((const float*)&vg[0])[j], ((const float*)&vg[1])[j],
                                          ((const float*)&vg[2])[j], ((const float*)&vg[3])[j]);
            *(float4*)(&spT[4 * f4 + j][r0]) = cp;
            *(float4*)(&sgT[4 * f4 + j][r0]) = cg;
        }
    }
    __syncthreads();

    // ---- vertical pass: thread = (col, row-group of 4); 44 cols x 8 groups = 352 tasks
    for (int t2 = tid; t2 < PAD * 8; t2 += 256) {
        const int c = t2 % PAD, rg = t2 / PAD;
        const float* pcol = &spT[c][0];
        const float* gcol = &sgT[c][0];
        float pv[16], gv[16];
#pragma unroll
        for (int i = 0; i < 4; ++i) {
            const float4 a = *(const float4*)(pcol + 4 * rg + 4 * i);
            const float4 b = *(const float4*)(gcol + 4 * rg + 4 * i);
            pv[4 * i + 0] = a.x; pv[4 * i + 1] = a.y; pv[4 * i + 2] = a.z; pv[4 * i + 3] = a.w;
            gv[4 * i + 0] = b.x; gv[4 * i + 1] = b.y; gv[4 * i + 2] = b.z; gv[4 * i + 3] = b.w;
        }
        float pp[14], gg[14], pg[14];
#pragma unroll
        for (int e = 0; e < 14; ++e) {
            pp[e] = pv[e] * pv[e];
            gg[e] = gv[e] * gv[e];
            pg[e] = pv[e] * gv[e];
        }
#pragma unroll
        for (int j = 0; j < 4; ++j) {
            float a0 = 0.f, a1 = 0.f, a2 = 0.f, a3 = 0.f, a4 = 0.f;
#pragma unroll
            for (int k = 0; k < WIN; ++k) {
                const float w = wgt[k];
                a0 += w * pv[j + k];
                a1 += w * gv[j + k];
                a2 += w * pp[j + k];
                a3 += w * gg[j + k];
                a4 += w * pg[j + k];
            }
            const int r = rg * 4 + j;
            sv[0][r][c] = a0; sv[1][r][c] = a1; sv[2][r][c] = a2;
            sv[3][r][c] = a3; sv[4][r][c] = a4;
        }
    }
    __syncthreads();

    // ---- horizontal pass + SSIM: thread = (row, col-group of 4); 32 x 8 = 256 tasks
    float lsum = 0.f;
    {
        const int r = tid >> 3;
        const int c0 = (tid & 7) * 4;
        float q[5][16];
#pragma unroll
        for (int qq = 0; qq < 5; ++qq) {
#pragma unroll
            for (int i = 0; i < 4; ++i) {
                const float4 a = *(const float4*)(&sv[qq][r][c0 + 4 * i]);
                q[qq][4 * i + 0] = a.x; q[qq][4 * i + 1] = a.y;
                q[qq][4 * i + 2] = a.z; q[qq][4 * i + 3] = a.w;
            }
        }
        const bool rowok = (oy0 + r) < OH;
#pragma unroll
        for (int cc = 0; cc < 4; ++cc) {
            float m1 = 0.f, m2 = 0.f, e11 = 0.f, e22 = 0.f, e12 = 0.f;
#pragma unroll
            for (int k = 0; k < WIN; ++k) {
                const float w = wgt[k];
                m1  += w * q[0][cc + k];
                m2  += w * q[1][cc + k];
                e11 += w * q[2][cc + k];
                e22 += w * q[3][cc + k];
                e12 += w * q[4][cc + k];
            }
            const float mu11 = m1 * m1, mu22 = m2 * m2, mu12 = m1 * m2;
            const float s11 = e11 - mu11, s22 = e22 - mu22, s12 = e12 - mu12;
            const float cs = (2.f * s12 + C2) / (s11 + s22 + C2);
            const float ssim = ((2.f * mu12 + C1) / (mu11 + mu22 + C1)) * cs;
            const bool ok = rowok && ((ox0 + c0 + cc) < OW);
            lsum += ok ? ssim : 0.f;
        }
    }

    // ---- block reduction: wave64 shuffle, then cross-wave via LDS
#pragma unroll
    for (int off = 32; off > 0; off >>= 1)
        lsum += __shfl_down(lsum, off, 64);

    __shared__ float wsum[4];
    const int wid = tid >> 6, lane = tid & 63;
    if (lane == 0) wsum[wid] = lsum;
    __syncthreads();
    if (tid == 0) {
        const float bs = wsum[0] + wsum[1] + wsum[2] + wsum[3];
        atomicAdd(acc, bs * (float)(1.0 / TOTAL));
    }
}

extern "C" void kernel_launch(void* const* d_in, const int* in_sizes, int n_in,
                              void* d_out, int out_size, void* d_ws, size_t ws_size,
                              hipStream_t stream) {
    const float* P = (const float*)d_in[0];   // predict
    const float* G = (const float*)d_in[1];   // gt
    float* out = (float*)d_out;
    float* acc = (float*)d_ws;

    zero_acc_kernel<<<1, 64, 0, stream>>>(acc);
    ssim_main_kernel<<<NIMG * 16 * 16, 256, 0, stream>>>(P, G, acc);
    finalize_kernel<<<1, 64, 0, stream>>>(acc, out);
}

// Round 4
// 83.609 us; speedup vs baseline: 1.5826x; 1.5551x over previous
//
#include <hip/hip_runtime.h>

// SSIM loss: predict/gt (32,1,512,512) f32, 11-tap separable gaussian (sigma=1.5),
// VALID padding -> 502x502 per image, loss = 1 - mean(ssim_map).
//
// Round 4: remove the single-address atomicAdd chain (theory: 8192 dependent
// same-address RMWs at ~16ns each == the entire 129us). Per-block plain store
// + one-block tree-reduce finalize. Main body otherwise identical to round 3.

constexpr int WIN = 11;
constexpr int TILE = 32;
constexpr int PAD = 44;                   // 42 used, padded to multiple of 4
constexpr int H = 512, W = 512, NIMG = 32;
constexpr int OH = H - WIN + 1, OW = W - WIN + 1;  // 502
constexpr int NBLK = NIMG * 16 * 16;      // 8192
constexpr float C1 = 0.009801f;   // (0.01*9.9)^2
constexpr float C2 = 0.088209f;   // (0.03*9.9)^2
constexpr double TOTAL = (double)NIMG * (double)OH * (double)OW;

__global__ __launch_bounds__(256) void ssim_main_kernel(const float* __restrict__ P,
                                                        const float* __restrict__ G,
                                                        float* __restrict__ blocksum) {
    // transposed input tiles: [col][row], column segments written as b128
    __shared__ float spT[PAD][PAD];
    __shared__ float sgT[PAD][PAD];
    // vertically blurred channels, row-major: [q][row][col]
    __shared__ float sv[5][TILE][PAD];

    const int tid = threadIdx.x;
    const int bid = blockIdx.x;
    const int img = bid >> 8;            // 256 tiles per image (16x16)
    const int t = bid & 255;
    const int oy0 = (t >> 4) * TILE;
    const int ox0 = (t & 15) * TILE;

    const float* p = P + (size_t)img * H * W;
    const float* g = G + (size_t)img * H * W;

    // gaussian weights
    float wgt[WIN];
    {
        float s = 0.f;
#pragma unroll
        for (int i = 0; i < WIN; ++i) {
            float c = (float)(i - WIN / 2);
            wgt[i] = __expf(-(c * c) / 4.5f);   // 2*sigma^2 = 4.5
            s += wgt[i];
        }
        float inv = 1.f / s;
#pragma unroll
        for (int i = 0; i < WIN; ++i) wgt[i] *= inv;
    }

    // ---- stage (register 4x4 transpose): 11 col-groups x 11 row-quads = 121 tasks
    for (int t2 = tid; t2 < 121; t2 += 256) {
        const int rq = t2 % 11, f4 = t2 / 11;
        const int gcol = ox0 + f4 * 4;
        float4 vp[4], vg[4];
#pragma unroll
        for (int i = 0; i < 4; ++i) {
            const int gr = min(oy0 + 4 * rq + i, H - 1);
            if (gcol + 3 < W) {
                vp[i] = *(const float4*)(p + gr * W + gcol);
                vg[i] = *(const float4*)(g + gr * W + gcol);
            } else {
                const int c0 = min(gcol, W - 1), c1 = min(gcol + 1, W - 1);
                const int c2 = min(gcol + 2, W - 1), c3 = min(gcol + 3, W - 1);
                vp[i] = make_float4(p[gr * W + c0], p[gr * W + c1], p[gr * W + c2], p[gr * W + c3]);
                vg[i] = make_float4(g[gr * W + c0], g[gr * W + c1], g[gr * W + c2], g[gr * W + c3]);
            }
        }
        const int r0 = 4 * rq;
#pragma unroll
        for (int j = 0; j < 4; ++j) {
            const float4 cp = make_float4(((const float*)&vp[0])[j], ((const float*)&vp[1])[j],
                                          ((const float*)&vp[2])[j], ((const float*)&vp[3])[j]);
            const float4 cg = make_float4(((const float*)&vg[0])[j], ((const float*)&vg[1])[j],
                                          ((const float*)&vg[2])[j], ((const float*)&vg[3])[j]);
            *(float4*)(&spT[4 * f4 + j][r0]) = cp;
            *(float4*)(&sgT[4 * f4 + j][r0]) = cg;
        }
    }
    __syncthreads();

    // ---- vertical pass: thread = (col, row-group of 4); 44 cols x 8 groups = 352 tasks
    for (int t2 = tid; t2 < PAD * 8; t2 += 256) {
        const int c = t2 % PAD, rg = t2 / PAD;
        const float* pcol = &spT[c][0];
        const float* gcol = &sgT[c][0];
        float pv[16], gv[16];
#pragma unroll
        for (int i = 0; i < 4; ++i) {
            const float4 a = *(const float4*)(pcol + 4 * rg + 4 * i);
            const float4 b = *(const float4*)(gcol + 4 * rg + 4 * i);
            pv[4 * i + 0] = a.x; pv[4 * i + 1] = a.y; pv[4 * i + 2] = a.z; pv[4 * i + 3] = a.w;
            gv[4 * i + 0] = b.x; gv[4 * i + 1] = b.y; gv[4 * i + 2] = b.z; gv[4 * i + 3] = b.w;
        }
        float pp[14], gg[14], pg[14];
#pragma unroll
        for (int e = 0; e < 14; ++e) {
            pp[e] = pv[e] * pv[e];
            gg[e] = gv[e] * gv[e];
            pg[e] = pv[e] * gv[e];
        }
#pragma unroll
        for (int j = 0; j < 4; ++j) {
            float a0 = 0.f, a1 = 0.f, a2 = 0.f, a3 = 0.f, a4 = 0.f;
#pragma unroll
            for (int k = 0; k < WIN; ++k) {
                const float w = wgt[k];
                a0 += w * pv[j + k];
                a1 += w * gv[j + k];
                a2 += w * pp[j + k];
                a3 += w * gg[j + k];
                a4 += w * pg[j + k];
            }
            const int r = rg * 4 + j;
            sv[0][r][c] = a0; sv[1][r][c] = a1; sv[2][r][c] = a2;
            sv[3][r][c] = a3; sv[4][r][c] = a4;
        }
    }
    __syncthreads();

    // ---- horizontal pass + SSIM: thread = (row, col-group of 4); 32 x 8 = 256 tasks
    float lsum = 0.f;
    {
        const int r = tid >> 3;
        const int c0 = (tid & 7) * 4;
        float q[5][16];
#pragma unroll
        for (int qq = 0; qq < 5; ++qq) {
#pragma unroll
            for (int i = 0; i < 4; ++i) {
                const float4 a = *(const float4*)(&sv[qq][r][c0 + 4 * i]);
                q[qq][4 * i + 0] = a.x; q[qq][4 * i + 1] = a.y;
                q[qq][4 * i + 2] = a.z; q[qq][4 * i + 3] = a.w;
            }
        }
        const bool rowok = (oy0 + r) < OH;
#pragma unroll
        for (int cc = 0; cc < 4; ++cc) {
            float m1 = 0.f, m2 = 0.f, e11 = 0.f, e22 = 0.f, e12 = 0.f;
#pragma unroll
            for (int k = 0; k < WIN; ++k) {
                const float w = wgt[k];
                m1  += w * q[0][cc + k];
                m2  += w * q[1][cc + k];
                e11 += w * q[2][cc + k];
                e22 += w * q[3][cc + k];
                e12 += w * q[4][cc + k];
            }
            const float mu11 = m1 * m1, mu22 = m2 * m2, mu12 = m1 * m2;
            const float s11 = e11 - mu11, s22 = e22 - mu22, s12 = e12 - mu12;
            const float cs = (2.f * s12 + C2) / (s11 + s22 + C2);
            const float ssim = ((2.f * mu12 + C1) / (mu11 + mu22 + C1)) * cs;
            const bool ok = rowok && ((ox0 + c0 + cc) < OW);
            lsum += ok ? ssim : 0.f;
        }
    }

    // ---- block reduction: wave64 shuffle, then cross-wave via LDS; plain store
#pragma unroll
    for (int off = 32; off > 0; off >>= 1)
        lsum += __shfl_down(lsum, off, 64);

    __shared__ float wsum[4];
    const int wid = tid >> 6, lane = tid & 63;
    if (lane == 0) wsum[wid] = lsum;
    __syncthreads();
    if (tid == 0) {
        blocksum[bid] = wsum[0] + wsum[1] + wsum[2] + wsum[3];
    }
}

// one-block reduction of 8192 block sums -> loss scalar
__global__ __launch_bounds__(256) void reduce_kernel(const float* __restrict__ blocksum,
                                                     float* __restrict__ out) {
    const int tid = threadIdx.x;
    float s = 0.f;
#pragma unroll
    for (int i = 0; i < 8; ++i) {
        const float4 v = ((const float4*)blocksum)[tid + 256 * i];
        s += (v.x + v.y) + (v.z + v.w);
    }
#pragma unroll
    for (int off = 32; off > 0; off >>= 1)
        s += __shfl_down(s, off, 64);

    __shared__ float wsum[4];
    const int wid = tid >> 6, lane = tid & 63;
    if (lane == 0) wsum[wid] = s;
    __syncthreads();
    if (tid == 0) {
        const float total = (wsum[0] + wsum[1]) + (wsum[2] + wsum[3]);
        out[0] = 1.f - total * (float)(1.0 / TOTAL);
    }
}

extern "C" void kernel_launch(void* const* d_in, const int* in_sizes, int n_in,
                              void* d_out, int out_size, void* d_ws, size_t ws_size,
                              hipStream_t stream) {
    const float* P = (const float*)d_in[0];   // predict
    const float* G = (const float*)d_in[1];   // gt
    float* out = (float*)d_out;
    float* blocksum = (float*)d_ws;           // NBLK floats

    ssim_main_kernel<<<NBLK, 256, 0, stream>>>(P, G, blocksum);
    reduce_kernel<<<1, 256, 0, stream>>>(blocksum, out);
}

// Round 5
// 60.133 us; speedup vs baseline: 2.2005x; 1.3904x over previous
//
#include <hip/hip_runtime.h>

// SSIM loss: predict/gt (32,1,512,512) f32, 11-tap separable gaussian (sigma=1.5),
// VALID padding -> 502x502 per image, loss = 1 - mean(ssim_map).
//
// Round 5: streaming column kernel, zero LDS data path. Thread = 1 output
// column x 64-row strip. Per input row: 22 coalesced global b32 loads (L1-hot),
// horizontal conv of 5 channels in registers, 11-deep register ring buffer
// (static indices via 11x unroll) for vertical conv + SSIM.

constexpr int WIN = 11;
constexpr int H = 512, W = 512, NIMG = 32;
constexpr int OH = H - WIN + 1, OW = W - WIN + 1;  // 502
constexpr int RPS = 64;                 // output rows per strip
constexpr int NSTRIP = 8;               // 8*64 = 512 >= 502
constexpr int NBLK = NIMG * NSTRIP * 2; // 512 blocks
constexpr float C1 = 0.009801f;   // (0.01*9.9)^2
constexpr float C2 = 0.088209f;   // (0.03*9.9)^2
constexpr double TOTAL = (double)NIMG * (double)OH * (double)OW;

// gaussian weights, sigma=1.5, normalized (computed in f64, rounded to f32)
__device__ constexpr float WGT[WIN] = {
    0.0010285f, 0.0075988f, 0.0360008f, 0.1093607f, 0.2130054f,
    0.2660118f,
    0.2130054f, 0.1093607f, 0.0360008f, 0.0075988f, 0.0010285f};

template <int U>
__device__ __forceinline__ void row_body(int base, int r0,
                                         const float* __restrict__ p,
                                         const float* __restrict__ g,
                                         float (&hp)[WIN], float (&hg)[WIN],
                                         float (&hpp)[WIN], float (&hgg)[WIN],
                                         float (&hpg)[WIN],
                                         bool active, float& lsum) {
    const int rin = base + U;
    const int rr = min(rin, H - 1);          // clamp (tail strip only)
    const float* rp = p + (size_t)rr * W;
    const float* rg = g + (size_t)rr * W;

    // horizontal 11-tap conv of p, g, p*p, g*g, p*g
    float a0 = 0.f, a1 = 0.f, a2 = 0.f, a3 = 0.f, a4 = 0.f;
#pragma unroll
    for (int k = 0; k < WIN; ++k) {
        const float pv = rp[k];
        const float gv = rg[k];
        const float w = WGT[k];
        const float wp = w * pv;
        a0 = fmaf(w, pv, a0);
        a1 = fmaf(w, gv, a1);
        a2 = fmaf(wp, pv, a2);
        a4 = fmaf(wp, gv, a4);
        a3 = fmaf(w * gv, gv, a3);
    }
    hp[U] = a0; hg[U] = a1; hpp[U] = a2; hgg[U] = a3; hpg[U] = a4;

    // vertical conv + SSIM for output row rin-10 (ring slots are static)
    const int ro = rin - (WIN - 1);
    if (ro >= r0 && ro < OH) {
        float m1 = 0.f, m2 = 0.f, e11 = 0.f, e22 = 0.f, e12 = 0.f;
#pragma unroll
        for (int k = 0; k < WIN; ++k) {
            const int s = (U + 1 + k) % WIN;   // compile-time after unroll
            const float w = WGT[k];
            m1  = fmaf(w, hp[s], m1);
            m2  = fmaf(w, hg[s], m2);
            e11 = fmaf(w, hpp[s], e11);
            e22 = fmaf(w, hgg[s], e22);
            e12 = fmaf(w, hpg[s], e12);
        }
        const float mu11 = m1 * m1, mu22 = m2 * m2, mu12 = m1 * m2;
        const float s11 = e11 - mu11, s22 = e22 - mu22, s12 = e12 - mu12;
        const float cs = __fdividef(2.f * s12 + C2, s11 + s22 + C2);
        const float ssim = __fdividef(2.f * mu12 + C1, mu11 + mu22 + C1) * cs;
        lsum += active ? ssim : 0.f;
    }
}

__global__ __launch_bounds__(256) void ssim_stream_kernel(const float* __restrict__ P,
                                                          const float* __restrict__ G,
                                                          float* __restrict__ blocksum) {
    const int tid = threadIdx.x;
    const int bid = blockIdx.x;
    const int img = bid >> 4;          // 16 blocks per image (8 strips x 2 col-halves)
    const int sb = bid & 15;
    const int strip = sb >> 1;
    const int cb = sb & 1;

    int col = cb * 256 + tid;          // 0..511
    const bool active = col < OW;      // 502
    if (!active) col = OW - 1;         // clamp: duplicate compute, masked from sum

    const int r0 = strip * RPS;        // first output row of this strip

    const float* p = P + (size_t)img * H * W + col;
    const float* g = G + (size_t)img * H * W + col;

    float hp[WIN], hg[WIN], hpp[WIN], hgg[WIN], hpg[WIN];
    float lsum = 0.f;

    // 74 input rows: 6 x 11 + 8 (ring slot = (i % 11), kept static by unroll)
    int base = r0;
#pragma unroll 1
    for (int ii = 0; ii < 6; ++ii, base += 11) {
        row_body<0>(base, r0, p, g, hp, hg, hpp, hgg, hpg, active, lsum);
        row_body<1>(base, r0, p, g, hp, hg, hpp, hgg, hpg, active, lsum);
        row_body<2>(base, r0, p, g, hp, hg, hpp, hgg, hpg, active, lsum);
        row_body<3>(base, r0, p, g, hp, hg, hpp, hgg, hpg, active, lsum);
        row_body<4>(base, r0, p, g, hp, hg, hpp, hgg, hpg, active, lsum);
        row_body<5>(base, r0, p, g, hp, hg, hpp, hgg, hpg, active, lsum);
        row_body<6>(base, r0, p, g, hp, hg, hpp, hgg, hpg, active, lsum);
        row_body<7>(base, r0, p, g, hp, hg, hpp, hgg, hpg, active, lsum);
        row_body<8>(base, r0, p, g, hp, hg, hpp, hgg, hpg, active, lsum);
        row_body<9>(base, r0, p, g, hp, hg, hpp, hgg, hpg, active, lsum);
        row_body<10>(base, r0, p, g, hp, hg, hpp, hgg, hpg, active, lsum);
    }
    // epilogue rows i = 66..73 (slots 0..7)
    row_body<0>(base, r0, p, g, hp, hg, hpp, hgg, hpg, active, lsum);
    row_body<1>(base, r0, p, g, hp, hg, hpp, hgg, hpg, active, lsum);
    row_body<2>(base, r0, p, g, hp, hg, hpp, hgg, hpg, active, lsum);
    row_body<3>(base, r0, p, g, hp, hg, hpp, hgg, hpg, active, lsum);
    row_body<4>(base, r0, p, g, hp, hg, hpp, hgg, hpg, active, lsum);
    row_body<5>(base, r0, p, g, hp, hg, hpp, hgg, hpg, active, lsum);
    row_body<6>(base, r0, p, g, hp, hg, hpp, hgg, hpg, active, lsum);
    row_body<7>(base, r0, p, g, hp, hg, hpp, hgg, hpg, active, lsum);

    // block reduction: wave64 shuffle, then cross-wave via LDS; plain store
#pragma unroll
    for (int off = 32; off > 0; off >>= 1)
        lsum += __shfl_down(lsum, off, 64);

    __shared__ float wsum[4];
    const int wid = tid >> 6, lane = tid & 63;
    if (lane == 0) wsum[wid] = lsum;
    __syncthreads();
    if (tid == 0) {
        blocksum[bid] = (wsum[0] + wsum[1]) + (wsum[2] + wsum[3]);
    }
}

// one-block reduction of 512 block sums -> loss scalar
__global__ __launch_bounds__(256) void reduce_kernel(const float* __restrict__ blocksum,
                                                     float* __restrict__ out) {
    const int tid = threadIdx.x;
    const float2 v = ((const float2*)blocksum)[tid];
    float s = v.x + v.y;
#pragma unroll
    for (int off = 32; off > 0; off >>= 1)
        s += __shfl_down(s, off, 64);

    __shared__ float wsum[4];
    const int wid = tid >> 6, lane = tid & 63;
    if (lane == 0) wsum[wid] = s;
    __syncthreads();
    if (tid == 0) {
        const float total = (wsum[0] + wsum[1]) + (wsum[2] + wsum[3]);
        out[0] = 1.f - total * (float)(1.0 / TOTAL);
    }
}

extern "C" void kernel_launch(void* const* d_in, const int* in_sizes, int n_in,
                              void* d_out, int out_size, void* d_ws, size_t ws_size,
                              hipStream_t stream) {
    const float* P = (const float*)d_in[0];   // predict
    const float* G = (const float*)d_in[1];   // gt
    float* out = (float*)d_out;
    float* blocksum = (float*)d_ws;           // NBLK floats

    ssim_stream_kernel<<<NBLK, 256, 0, stream>>>(P, G, blocksum);
    reduce_kernel<<<1, 256, 0, stream>>>(blocksum, out);
}